// Round 19
// baseline (245.243 us; speedup 1.0000x reference)
//
#include <hip/hip_runtime.h>

typedef unsigned short u16;
typedef __attribute__((ext_vector_type(8))) short bf16x8;
typedef __attribute__((ext_vector_type(4))) float f32x4;

__device__ __forceinline__ u16 f2bf(float f) {
  union { float fv; unsigned u; } v; v.fv = f;
  unsigned r = v.u + 0x7fffu + ((v.u >> 16) & 1u);
  return (u16)(r >> 16);
}

__device__ __forceinline__ void gload_lds16(const void* g, void* l) {
  __builtin_amdgcn_global_load_lds(
      (const __attribute__((address_space(1))) unsigned*)g,
      (__attribute__((address_space(3))) unsigned*)l, 16, 0, 0);
}

// XOR-swizzle for LDS tiles with 128B rows (attn K/V/P tiles).
__device__ __forceinline__ int swz128(int o) { return o ^ ((o >> 3) & 0x70); }
// XOR-swizzle for LDS tiles with 64B rows (GEMM tiles).
__device__ __forceinline__ int swz64(int o) { return o ^ (((o >> 7) & 3) << 4); }

// ---- f2bf x16 helper --------------------------------------------------------
__device__ __forceinline__ void cvt16(const float* __restrict__ x,
                                      u16* __restrict__ y, int i) {
  uint4 o0, o1;
  const float4 v0 = *(const float4*)(x + i);
  const float4 v1 = *(const float4*)(x + i + 4);
  const float4 v2 = *(const float4*)(x + i + 8);
  const float4 v3 = *(const float4*)(x + i + 12);
  o0.x = (unsigned)f2bf(v0.x) | ((unsigned)f2bf(v0.y) << 16);
  o0.y = (unsigned)f2bf(v0.z) | ((unsigned)f2bf(v0.w) << 16);
  o0.z = (unsigned)f2bf(v1.x) | ((unsigned)f2bf(v1.y) << 16);
  o0.w = (unsigned)f2bf(v1.z) | ((unsigned)f2bf(v1.w) << 16);
  o1.x = (unsigned)f2bf(v2.x) | ((unsigned)f2bf(v2.y) << 16);
  o1.y = (unsigned)f2bf(v2.z) | ((unsigned)f2bf(v2.w) << 16);
  o1.z = (unsigned)f2bf(v3.x) | ((unsigned)f2bf(v3.y) << 16);
  o1.w = (unsigned)f2bf(v3.z) | ((unsigned)f2bf(v3.w) << 16);
  *(uint4*)(y + i) = o0;
  *(uint4*)(y + i + 8) = o1;
}

// ---- elementwise f32 -> bf16, 16 elems/thread (serial fallback path) --------
__global__ __launch_bounds__(256) void cvt_bf16_kernel(const float* __restrict__ x,
                                                       u16* __restrict__ y) {
  cvt16(x, y, (blockIdx.x * 256 + threadIdx.x) * 16);
}

// ---- all three inputs f32 -> bf16 in ONE dispatch (z selects input) ---------
__global__ __launch_bounds__(256) void cvt3_bf16_kernel(
    const float* __restrict__ x0, const float* __restrict__ x1,
    const float* __restrict__ x2,
    u16* __restrict__ y0, u16* __restrict__ y1, u16* __restrict__ y2) {
  const int z = blockIdx.z;
  const float* x = z == 0 ? x0 : z == 1 ? x1 : x2;
  u16* y = z == 0 ? y0 : z == 1 ? y1 : y2;
  cvt16(x, y, (blockIdx.x * 256 + threadIdx.x) * 16);
}

// ---- all 4 weights (1024x1024 f32, k-major) -> WT (n-major bf16), one pass --
__global__ __launch_bounds__(256) void transpose_cvt4_kernel(
    const float* __restrict__ W0, const float* __restrict__ W1,
    const float* __restrict__ W2, const float* __restrict__ W3,
    u16* __restrict__ T0, u16* __restrict__ T1,
    u16* __restrict__ T2, u16* __restrict__ T3) {
  __shared__ float tile[32][33];
  const int z = blockIdx.z;
  const float* W = z == 0 ? W0 : z == 1 ? W1 : z == 2 ? W2 : W3;
  u16* WT = z == 0 ? T0 : z == 1 ? T1 : z == 2 ? T2 : T3;
  const int bx = blockIdx.x * 32, by = blockIdx.y * 32;
  const int tx = threadIdx.x, ty = threadIdx.y;
  #pragma unroll
  for (int i = 0; i < 32; i += 8)
    tile[ty + i][tx] = W[(size_t)(by + ty + i) * 1024 + bx + tx];
  __syncthreads();
  #pragma unroll
  for (int i = 0; i < 32; i += 8)
    WT[(size_t)(bx + ty + i) * 1024 + by + tx] = f2bf(tile[tx][ty + i]);
}

// ---- merged QKV projection GEMM: 1536 blocks, one dispatch ------------------
// Byte-identical 8-wave 128x128 body (r15-proven); proj = lg>>9 selects
// {A, W^T, bias, epilogue} (select indexing proven in r12/r13). XCD-chunked:
// lg = (bid&7)*192 + bid>>3 so each XCD walks contiguous tiles.
__global__ __launch_bounds__(512) void qkv_gemm_kernel(
    const u16* __restrict__ Aq, const u16* __restrict__ Ak,
    const u16* __restrict__ Av,
    const u16* __restrict__ WTq, const u16* __restrict__ WTk,
    const u16* __restrict__ WTv,
    const float* __restrict__ bqp, const float* __restrict__ bkp,
    const float* __restrict__ bvp,
    u16* __restrict__ qhd, u16* __restrict__ khd, u16* __restrict__ vtd) {
  __shared__ u16 As[128 * 32];
  __shared__ u16 Bs[128 * 32];
  const int tid = threadIdx.x;
  const int w = tid >> 6, lane = tid & 63;
  const int wr = w >> 1, wc = w & 1;      // wave -> (row32, col64) sub-tile
  const int l16 = lane & 15, lhi = lane >> 4;
  const int lg = (blockIdx.x & 7) * 192 + (blockIdx.x >> 3);
  const int proj = lg >> 9, inner = lg & 511;
  const int m0 = (inner >> 3) * 128, n0 = (inner & 7) * 128;
  const u16* A  = proj == 0 ? Aq : proj == 1 ? Ak : Av;
  const u16* BT = proj == 0 ? WTq : proj == 1 ? WTk : WTv;
  const float* bias = proj == 0 ? bqp : proj == 1 ? bkp : bvp;

  f32x4 acc[2][4] = {};

  for (int kt = 0; kt < 32; ++kt) {
    {
      const int ob = w * 1024;
      const int os = swz64(ob + (lane << 4));
      const int row = os >> 6, kb = os & 63;
      gload_lds16((const char*)A + (((size_t)(m0 + row)) << 11) + (kt << 6) + kb,
                  (char*)As + ob);
      gload_lds16((const char*)BT + (((size_t)(n0 + row)) << 11) + (kt << 6) + kb,
                  (char*)Bs + ob);
    }
    __syncthreads();
    bf16x8 a[2], b[4];
    #pragma unroll
    for (int i = 0; i < 2; ++i)
      a[i] = *(const bf16x8*)((const char*)As +
             swz64((wr * 32 + i * 16 + l16) * 64 + lhi * 16));
    #pragma unroll
    for (int j = 0; j < 4; ++j)
      b[j] = *(const bf16x8*)((const char*)Bs +
             swz64((wc * 64 + j * 16 + l16) * 64 + lhi * 16));
    #pragma unroll
    for (int i = 0; i < 2; ++i)
      #pragma unroll
      for (int j = 0; j < 4; ++j)
        acc[i][j] = __builtin_amdgcn_mfma_f32_16x16x32_bf16(a[i], b[j], acc[i][j], 0, 0, 0);
    __syncthreads();
  }

  #pragma unroll
  for (int i = 0; i < 2; ++i) {
    #pragma unroll
    for (int j = 0; j < 4; ++j) {
      const int n = n0 + wc * 64 + j * 16 + l16;
      const float bn = bias[n];
      #pragma unroll
      for (int r = 0; r < 4; ++r) {
        const int m = m0 + wr * 32 + i * 16 + lhi * 4 + r;
        float v = acc[i][j][r] + bn;
        const int bb = m >> 11, t = m & 2047, h = n >> 6, d = n & 63;
        if (proj == 0) {
          v *= 0.18033688f;  // (1/sqrt(DK)) * log2(e): softmax in exp2 domain
          qhd[((((size_t)bb * 16 + h) * 2048 + t) << 6) + d] = f2bf(v);
        } else if (proj == 1) {
          khd[((((size_t)bb * 16 + h) * 2048 + t) << 6) + d] = f2bf(v);
        } else {
          vtd[(((size_t)bb * 16 + h) * 64 + d) * 2048 + t] = f2bf(v);
        }
      }
    }
  }
}

// ---- 128x128-tile bf16 GEMM, 8 waves (512 thr): wave = 32x64 sub-tile -------
// (r15-proven.) 16KB LDS / swz64 / 2-barrier; XCD-chunked 512-block grid.
// MODE 0: q ; MODE 1: k ; MODE 2: v^T ; MODE 3: f32 out + bias
template <int MODE>
__global__ __launch_bounds__(512) void gemm128_kernel(
    const u16* __restrict__ A, const u16* __restrict__ BT,
    const float* __restrict__ bias, void* __restrict__ out) {
  __shared__ u16 As[128 * 32];
  __shared__ u16 Bs[128 * 32];
  const int tid = threadIdx.x;
  const int w = tid >> 6, lane = tid & 63;
  const int wr = w >> 1, wc = w & 1;
  const int l16 = lane & 15, lhi = lane >> 4;
  const int lg = (blockIdx.x & 7) * 64 + (blockIdx.x >> 3);  // XCD-chunk swizzle
  const int m0 = (lg >> 3) * 128, n0 = (lg & 7) * 128;

  f32x4 acc[2][4] = {};

  for (int kt = 0; kt < 32; ++kt) {
    {
      const int ob = w * 1024;
      const int os = swz64(ob + (lane << 4));
      const int row = os >> 6, kb = os & 63;
      gload_lds16((const char*)A + (((size_t)(m0 + row)) << 11) + (kt << 6) + kb,
                  (char*)As + ob);
      gload_lds16((const char*)BT + (((size_t)(n0 + row)) << 11) + (kt << 6) + kb,
                  (char*)Bs + ob);
    }
    __syncthreads();
    bf16x8 a[2], b[4];
    #pragma unroll
    for (int i = 0; i < 2; ++i)
      a[i] = *(const bf16x8*)((const char*)As +
             swz64((wr * 32 + i * 16 + l16) * 64 + lhi * 16));
    #pragma unroll
    for (int j = 0; j < 4; ++j)
      b[j] = *(const bf16x8*)((const char*)Bs +
             swz64((wc * 64 + j * 16 + l16) * 64 + lhi * 16));
    #pragma unroll
    for (int i = 0; i < 2; ++i)
      #pragma unroll
      for (int j = 0; j < 4; ++j)
        acc[i][j] = __builtin_amdgcn_mfma_f32_16x16x32_bf16(a[i], b[j], acc[i][j], 0, 0, 0);
    __syncthreads();
  }

  #pragma unroll
  for (int i = 0; i < 2; ++i) {
    #pragma unroll
    for (int j = 0; j < 4; ++j) {
      const int n = n0 + wc * 64 + j * 16 + l16;
      const float bn = bias[n];
      #pragma unroll
      for (int r = 0; r < 4; ++r) {
        const int m = m0 + wr * 32 + i * 16 + lhi * 4 + r;
        float v = acc[i][j][r] + bn;
        const int bb = m >> 11, t = m & 2047, h = n >> 6, d = n & 63;
        if constexpr (MODE == 0) {
          v *= 0.18033688f;
          ((u16*)out)[((((size_t)bb * 16 + h) * 2048 + t) << 6) + d] = f2bf(v);
        } else if constexpr (MODE == 1) {
          ((u16*)out)[((((size_t)bb * 16 + h) * 2048 + t) << 6) + d] = f2bf(v);
        } else if constexpr (MODE == 2) {
          ((u16*)out)[(((size_t)bb * 16 + h) * 64 + d) * 2048 + t] = f2bf(v);
        } else {
          ((float*)out)[(size_t)m * 1024 + n] = v;
        }
      }
    }
  }
}

// ---- flash attention: 1 block = (b, h, 128 q-rows); 8 waves x 16 rows -------
// (r15-proven: 110.5us.) K dbuf, V single-buffer (mid-tile barrier); full
// 2KB/wave P buffer; 40KB LDS; grid 1024 = 256CU x 4 (no tail).
// Fixed-max softmax in MFMA C-init; ones-MFMA row-sum; setprio; XCD swizzle.
__global__ __launch_bounds__(512) void attn_kernel(
    const u16* __restrict__ qh, const u16* __restrict__ kh,
    const u16* __restrict__ vth, u16* __restrict__ outPre) {
  __shared__ u16 Kbuf[2][64 * 64];  // [buf][key][d], swizzled 128B rows
  __shared__ u16 Vbuf[64 * 64];     // [d][key], swizzled 128B rows
  __shared__ u16 Pl[8][16 * 64];    // per-wave P tile [qrow][key], swizzled

  const int tid = threadIdx.x, w = tid >> 6, lane = tid & 63;
  const int l16 = lane & 15, lhi = lane >> 4;

  const int wg = (blockIdx.x & 7) * 128 + (blockIdx.x >> 3);
  const int qt = wg & 15, hb = wg >> 4;
  const int h = hb & 15, b = hb >> 4;

  const size_t bh = (size_t)b * 16 + h;
  const u16* qb = qh + bh * (2048 * 64);
  const u16* kb = kh + bh * (2048 * 64);
  const u16* vb = vth + bh * (64 * 2048);

  const int qr0 = qt * 128 + w * 16;
  bf16x8 aq[2];
  #pragma unroll
  for (int c = 0; c < 2; ++c)
    aq[c] = *(const bf16x8*)(qb + (qr0 + l16) * 64 + c * 32 + lhi * 8);

  bf16x8 ones;
  #pragma unroll
  for (int e = 0; e < 8; ++e) ones[e] = (short)0x3F80;  // bf16 1.0

  f32x4 acc_o[4] = {};
  f32x4 acc_l = {};

  auto stageK = [&](int buf, int kv) {
    char* Kt = (char*)&Kbuf[buf][0];
    const int ob = w * 1024;
    const int os = swz128(ob + (lane << 4));
    gload_lds16((const char*)kb + ((size_t)kv << 7) + os, Kt + ob);
  };
  auto stageV = [&](int kv) {
    char* Vt = (char*)&Vbuf[0];
    const int ob = w * 1024;
    const int os = swz128(ob + (lane << 4));
    const int dd = os >> 7, j0 = (os & 127) >> 1;
    gload_lds16((const char*)vb + ((size_t)dd << 12) + (((size_t)(kv + j0)) << 1),
                Vt + ob);
  };

  stageK(0, 0);

  for (int t = 0; t < 32; ++t) {
    const int buf = t & 1;
    __syncthreads();   // K(t) ready; Vbuf consumed by prev tile
    stageV(t * 64);    // V(t) in flight; drains at the mid barrier

    const char* Kt = (const char*)&Kbuf[buf][0];

    // S = q.k^T - 4 (C-init). Fixed-max softmax: scores exp2-domain
    // ~N(0,0.59), global max ~3.7 < 4 -> p in (0,1]; offset-invariant.
    f32x4 s[4];
    #pragma unroll
    for (int jt = 0; jt < 4; ++jt) s[jt] = f32x4{-4.f, -4.f, -4.f, -4.f};
    __builtin_amdgcn_s_setprio(1);
    #pragma unroll
    for (int c = 0; c < 2; ++c) {
      #pragma unroll
      for (int jt = 0; jt < 4; ++jt) {
        const bf16x8 bk = *(const bf16x8*)(Kt +
            swz128((jt * 16 + l16) * 128 + c * 64 + lhi * 16));
        s[jt] = __builtin_amdgcn_mfma_f32_16x16x32_bf16(aq[c], bk, s[jt], 0, 0, 0);
      }
    }
    __builtin_amdgcn_s_setprio(0);

    #pragma unroll
    for (int jt = 0; jt < 4; ++jt)
      #pragma unroll
      for (int r = 0; r < 4; ++r)
        s[jt][r] = __builtin_amdgcn_exp2f(s[jt][r]);

    // P -> per-wave LDS (C-layout -> A-layout transpose), swizzled.
    char* Pw = (char*)&Pl[w][0];
    #pragma unroll
    for (int jt = 0; jt < 4; ++jt)
      #pragma unroll
      for (int r = 0; r < 4; ++r) {
        union { float f; unsigned u; } pv;
        pv.f = s[jt][r];
        *(u16*)(Pw + swz128((lhi * 4 + r) * 128 + (jt * 16 + l16) * 2)) =
            (u16)((pv.u + 0x8000u) >> 16);
      }

    __syncthreads();   // V(t) ready
    if (t < 31) stageK(buf ^ 1, (t + 1) * 64);

    const char* Vt = (const char*)&Vbuf[0];

    // O += P @ V ; row-sum via ones-B MFMA
    __builtin_amdgcn_s_setprio(1);
    #pragma unroll
    for (int c = 0; c < 2; ++c) {
      const bf16x8 ap = *(const bf16x8*)(Pw +
          swz128(l16 * 128 + c * 64 + lhi * 16));
      acc_l = __builtin_amdgcn_mfma_f32_16x16x32_bf16(ap, ones, acc_l, 0, 0, 0);
      #pragma unroll
      for (int dt = 0; dt < 4; ++dt) {
        const bf16x8 bv = *(const bf16x8*)(Vt +
            swz128((dt * 16 + l16) * 128 + c * 64 + lhi * 16));
        acc_o[dt] = __builtin_amdgcn_mfma_f32_16x16x32_bf16(ap, bv, acc_o[dt], 0, 0, 0);
      }
    }
    __builtin_amdgcn_s_setprio(0);
  }

  // faithful-reshape write: row = h*128 + t/16, col = (t%16)*64 + d
  #pragma unroll
  for (int dt = 0; dt < 4; ++dt) {
    #pragma unroll
    for (int r = 0; r < 4; ++r) {
      const int t = qr0 + lhi * 4 + r;
      const int d = dt * 16 + l16;
      const float v = acc_o[dt][r] / acc_l[r];
      const int rr = h * 128 + (t >> 4);
      const int cc = ((t & 15) << 6) + d;
      outPre[((size_t)b * 2048 + rr) * 1024 + cc] = f2bf(v);
    }
  }
}

extern "C" void kernel_launch(void* const* d_in, const int* in_sizes, int n_in,
                              void* d_out, int out_size, void* d_ws, size_t ws_size,
                              hipStream_t stream) {
  const float* Q  = (const float*)d_in[0];
  const float* K  = (const float*)d_in[1];
  const float* V  = (const float*)d_in[2];
  const float* Wq = (const float*)d_in[3];
  const float* bq = (const float*)d_in[4];
  const float* Wk = (const float*)d_in[5];
  const float* bk = (const float*)d_in[6];
  const float* Wv = (const float*)d_in[7];
  const float* bv = (const float*)d_in[8];
  const float* Wo = (const float*)d_in[9];
  const float* bo = (const float*)d_in[10];

  char* ws = (char*)d_ws;
  const size_t ACT = 16777216;              // 8192*1024 bf16 = 16MB
  const size_t WSZ = 2097152;               // 1024*1024 bf16 = 2MB
  u16* act = (u16*)(ws);                    // outPre (attn output, phase 3+)
  u16* qhd = (u16*)(ws + ACT);
  u16* khd = (u16*)(ws + 2 * ACT);
  u16* vtd = (u16*)(ws + 3 * ACT);
  u16* wtq = (u16*)(ws + 4 * ACT);
  u16* wtk = (u16*)(ws + 4 * ACT + WSZ);
  u16* wtv = (u16*)(ws + 4 * ACT + 2 * WSZ);
  u16* wto = (u16*)(ws + 4 * ACT + 3 * WSZ);

  const int cvtBlocks = 8388608 / 16 / 256;  // 2048 blocks per input

  // 1) all 4 weight transposes, one dispatch
  transpose_cvt4_kernel<<<dim3(32, 32, 4), dim3(32, 8), 0, stream>>>(
      Wq, Wk, Wv, Wo, wtq, wtk, wtv, wto);

  const size_t needBig = 4 * ACT + 4 * WSZ + 2 * ACT;  // 104 MB
  if (ws_size >= needBig) {
    // 2) batched: one cvt3 dispatch + ONE merged 1536-block QKV GEMM dispatch
    u16* abfQ = act;                                   // overlays outPre
    u16* abfK = (u16*)(ws + 4 * ACT + 4 * WSZ);
    u16* abfV = (u16*)(ws + 4 * ACT + 4 * WSZ + ACT);
    cvt3_bf16_kernel<<<dim3(cvtBlocks, 1, 3), 256, 0, stream>>>(
        Q, K, V, abfQ, abfK, abfV);
    qkv_gemm_kernel<<<1536, 512, 0, stream>>>(abfQ, abfK, abfV,
                                              wtq, wtk, wtv,
                                              bq, bk, bv, qhd, khd, vtd);
  } else {
    // serial fallback (r17-proven): one abf buffer reused
    u16* abf = act;
    cvt_bf16_kernel<<<cvtBlocks, 256, 0, stream>>>(Q, abf);
    gemm128_kernel<0><<<512, 512, 0, stream>>>(abf, wtq, bq, qhd);
    cvt_bf16_kernel<<<cvtBlocks, 256, 0, stream>>>(K, abf);
    gemm128_kernel<1><<<512, 512, 0, stream>>>(abf, wtk, bk, khd);
    cvt_bf16_kernel<<<cvtBlocks, 256, 0, stream>>>(V, abf);
    gemm128_kernel<2><<<512, 512, 0, stream>>>(abf, wtv, bv, vtd);
  }

  // 3) attention -> outPre (clobbers abfQ region, already consumed)
  attn_kernel<<<1024, 512, 0, stream>>>(qhd, khd, vtd, act);
  // 4) out = outPre @ Wo + bo (f32)
  gemm128_kernel<3><<<512, 512, 0, stream>>>(act, wto, bo, (float*)d_out);
}

// Round 20
// 225.207 us; speedup vs baseline: 1.0890x; 1.0890x over previous
//
#include <hip/hip_runtime.h>

typedef unsigned short u16;
typedef __attribute__((ext_vector_type(8))) short bf16x8;
typedef __attribute__((ext_vector_type(4))) float f32x4;

__device__ __forceinline__ u16 f2bf(float f) {
  union { float fv; unsigned u; } v; v.fv = f;
  unsigned r = v.u + 0x7fffu + ((v.u >> 16) & 1u);
  return (u16)(r >> 16);
}

__device__ __forceinline__ void gload_lds16(const void* g, void* l) {
  __builtin_amdgcn_global_load_lds(
      (const __attribute__((address_space(1))) unsigned*)g,
      (__attribute__((address_space(3))) unsigned*)l, 16, 0, 0);
}

// XOR-swizzle for LDS tiles with 128B rows (attn K/V/P tiles).
__device__ __forceinline__ int swz128(int o) { return o ^ ((o >> 3) & 0x70); }
// XOR-swizzle for LDS tiles with 64B rows (GEMM tiles).
__device__ __forceinline__ int swz64(int o) { return o ^ (((o >> 7) & 3) << 4); }

// ---- f2bf x16 helper --------------------------------------------------------
__device__ __forceinline__ void cvt16(const float* __restrict__ x,
                                      u16* __restrict__ y, int i) {
  uint4 o0, o1;
  const float4 v0 = *(const float4*)(x + i);
  const float4 v1 = *(const float4*)(x + i + 4);
  const float4 v2 = *(const float4*)(x + i + 8);
  const float4 v3 = *(const float4*)(x + i + 12);
  o0.x = (unsigned)f2bf(v0.x) | ((unsigned)f2bf(v0.y) << 16);
  o0.y = (unsigned)f2bf(v0.z) | ((unsigned)f2bf(v0.w) << 16);
  o0.z = (unsigned)f2bf(v1.x) | ((unsigned)f2bf(v1.y) << 16);
  o0.w = (unsigned)f2bf(v1.z) | ((unsigned)f2bf(v1.w) << 16);
  o1.x = (unsigned)f2bf(v2.x) | ((unsigned)f2bf(v2.y) << 16);
  o1.y = (unsigned)f2bf(v2.z) | ((unsigned)f2bf(v2.w) << 16);
  o1.z = (unsigned)f2bf(v3.x) | ((unsigned)f2bf(v3.y) << 16);
  o1.w = (unsigned)f2bf(v3.z) | ((unsigned)f2bf(v3.w) << 16);
  *(uint4*)(y + i) = o0;
  *(uint4*)(y + i + 8) = o1;
}

// ---- elementwise f32 -> bf16, 16 elems/thread (serial fallback path) --------
__global__ __launch_bounds__(256) void cvt_bf16_kernel(const float* __restrict__ x,
                                                       u16* __restrict__ y) {
  cvt16(x, y, (blockIdx.x * 256 + threadIdx.x) * 16);
}

// ---- all three inputs f32 -> bf16 in ONE dispatch (z selects input) ---------
__global__ __launch_bounds__(256) void cvt3_bf16_kernel(
    const float* __restrict__ x0, const float* __restrict__ x1,
    const float* __restrict__ x2,
    u16* __restrict__ y0, u16* __restrict__ y1, u16* __restrict__ y2) {
  const int z = blockIdx.z;
  const float* x = z == 0 ? x0 : z == 1 ? x1 : x2;
  u16* y = z == 0 ? y0 : z == 1 ? y1 : y2;
  cvt16(x, y, (blockIdx.x * 256 + threadIdx.x) * 16);
}

// ---- all 4 weights (1024x1024 f32, k-major) -> WT (n-major bf16), one pass --
__global__ __launch_bounds__(256) void transpose_cvt4_kernel(
    const float* __restrict__ W0, const float* __restrict__ W1,
    const float* __restrict__ W2, const float* __restrict__ W3,
    u16* __restrict__ T0, u16* __restrict__ T1,
    u16* __restrict__ T2, u16* __restrict__ T3) {
  __shared__ float tile[32][33];
  const int z = blockIdx.z;
  const float* W = z == 0 ? W0 : z == 1 ? W1 : z == 2 ? W2 : W3;
  u16* WT = z == 0 ? T0 : z == 1 ? T1 : z == 2 ? T2 : T3;
  const int bx = blockIdx.x * 32, by = blockIdx.y * 32;
  const int tx = threadIdx.x, ty = threadIdx.y;
  #pragma unroll
  for (int i = 0; i < 32; i += 8)
    tile[ty + i][tx] = W[(size_t)(by + ty + i) * 1024 + bx + tx];
  __syncthreads();
  #pragma unroll
  for (int i = 0; i < 32; i += 8)
    WT[(size_t)(bx + ty + i) * 1024 + by + tx] = f2bf(tile[tx][ty + i]);
}

// ---- 128x128-tile bf16 GEMM, 8 waves (512 thr): wave = 32x64 sub-tile -------
// (r15-proven.) 16KB LDS / swz64 / 2-barrier; XCD-chunked 512-block grid
// (each XCD owns 8 M-panels = 2MB A + 2MB W: exactly L2-resident — merging
// projections into one 1536-block dispatch overflowed L2 and cost 19us, r19).
// MODE 0: q -> (B,H,T,64) bf16, scaled by (1/8)*log2(e) ; MODE 1: k
// MODE 2: v -> (B,H,64,T) transposed        ; MODE 3: f32 out + bias
template <int MODE>
__global__ __launch_bounds__(512) void gemm128_kernel(
    const u16* __restrict__ A, const u16* __restrict__ BT,
    const float* __restrict__ bias, void* __restrict__ out) {
  __shared__ u16 As[128 * 32];
  __shared__ u16 Bs[128 * 32];
  const int tid = threadIdx.x;
  const int w = tid >> 6, lane = tid & 63;
  const int wr = w >> 1, wc = w & 1;      // wave -> (row32, col64) sub-tile
  const int l16 = lane & 15, lhi = lane >> 4;
  const int lg = (blockIdx.x & 7) * 64 + (blockIdx.x >> 3);  // XCD-chunk swizzle
  const int m0 = (lg >> 3) * 128, n0 = (lg & 7) * 128;

  f32x4 acc[2][4] = {};

  for (int kt = 0; kt < 32; ++kt) {
    {
      const int ob = w * 1024;
      const int os = swz64(ob + (lane << 4));
      const int row = os >> 6, kb = os & 63;
      gload_lds16((const char*)A + (((size_t)(m0 + row)) << 11) + (kt << 6) + kb,
                  (char*)As + ob);
      gload_lds16((const char*)BT + (((size_t)(n0 + row)) << 11) + (kt << 6) + kb,
                  (char*)Bs + ob);
    }
    __syncthreads();
    bf16x8 a[2], b[4];
    #pragma unroll
    for (int i = 0; i < 2; ++i)
      a[i] = *(const bf16x8*)((const char*)As +
             swz64((wr * 32 + i * 16 + l16) * 64 + lhi * 16));
    #pragma unroll
    for (int j = 0; j < 4; ++j)
      b[j] = *(const bf16x8*)((const char*)Bs +
             swz64((wc * 64 + j * 16 + l16) * 64 + lhi * 16));
    #pragma unroll
    for (int i = 0; i < 2; ++i)
      #pragma unroll
      for (int j = 0; j < 4; ++j)
        acc[i][j] = __builtin_amdgcn_mfma_f32_16x16x32_bf16(a[i], b[j], acc[i][j], 0, 0, 0);
    __syncthreads();
  }

  #pragma unroll
  for (int i = 0; i < 2; ++i) {
    #pragma unroll
    for (int j = 0; j < 4; ++j) {
      const int n = n0 + wc * 64 + j * 16 + l16;
      const float bn = bias[n];
      #pragma unroll
      for (int r = 0; r < 4; ++r) {
        const int m = m0 + wr * 32 + i * 16 + lhi * 4 + r;
        float v = acc[i][j][r] + bn;
        const int bb = m >> 11, t = m & 2047, h = n >> 6, d = n & 63;
        if constexpr (MODE == 0) {
          v *= 0.18033688f;  // (1/sqrt(DK)) * log2(e): softmax in exp2 domain
          ((u16*)out)[((((size_t)bb * 16 + h) * 2048 + t) << 6) + d] = f2bf(v);
        } else if constexpr (MODE == 1) {
          ((u16*)out)[((((size_t)bb * 16 + h) * 2048 + t) << 6) + d] = f2bf(v);
        } else if constexpr (MODE == 2) {
          ((u16*)out)[(((size_t)bb * 16 + h) * 64 + d) * 2048 + t] = f2bf(v);
        } else {
          ((float*)out)[(size_t)m * 1024 + n] = v;
        }
      }
    }
  }
}

// ---- flash attention: 1 block = (b, h, 128 q-rows); 8 waves x 16 rows -------
// (r15-proven: 110.5us.) K dbuf, V single-buffer (mid-tile barrier); full
// 2KB/wave P buffer; 40KB LDS; grid 1024 = 256CU x 4 (no tail).
// Fixed-max softmax in MFMA C-init; ones-MFMA row-sum; setprio; XCD swizzle.
__global__ __launch_bounds__(512) void attn_kernel(
    const u16* __restrict__ qh, const u16* __restrict__ kh,
    const u16* __restrict__ vth, u16* __restrict__ outPre) {
  __shared__ u16 Kbuf[2][64 * 64];  // [buf][key][d], swizzled 128B rows
  __shared__ u16 Vbuf[64 * 64];     // [d][key], swizzled 128B rows
  __shared__ u16 Pl[8][16 * 64];    // per-wave P tile [qrow][key], swizzled

  const int tid = threadIdx.x, w = tid >> 6, lane = tid & 63;
  const int l16 = lane & 15, lhi = lane >> 4;

  const int wg = (blockIdx.x & 7) * 128 + (blockIdx.x >> 3);
  const int qt = wg & 15, hb = wg >> 4;
  const int h = hb & 15, b = hb >> 4;

  const size_t bh = (size_t)b * 16 + h;
  const u16* qb = qh + bh * (2048 * 64);
  const u16* kb = kh + bh * (2048 * 64);
  const u16* vb = vth + bh * (64 * 2048);

  const int qr0 = qt * 128 + w * 16;
  bf16x8 aq[2];
  #pragma unroll
  for (int c = 0; c < 2; ++c)
    aq[c] = *(const bf16x8*)(qb + (qr0 + l16) * 64 + c * 32 + lhi * 8);

  bf16x8 ones;
  #pragma unroll
  for (int e = 0; e < 8; ++e) ones[e] = (short)0x3F80;  // bf16 1.0

  f32x4 acc_o[4] = {};
  f32x4 acc_l = {};

  auto stageK = [&](int buf, int kv) {
    char* Kt = (char*)&Kbuf[buf][0];
    const int ob = w * 1024;
    const int os = swz128(ob + (lane << 4));
    gload_lds16((const char*)kb + ((size_t)kv << 7) + os, Kt + ob);
  };
  auto stageV = [&](int kv) {
    char* Vt = (char*)&Vbuf[0];
    const int ob = w * 1024;
    const int os = swz128(ob + (lane << 4));
    const int dd = os >> 7, j0 = (os & 127) >> 1;
    gload_lds16((const char*)vb + ((size_t)dd << 12) + (((size_t)(kv + j0)) << 1),
                Vt + ob);
  };

  stageK(0, 0);

  for (int t = 0; t < 32; ++t) {
    const int buf = t & 1;
    __syncthreads();   // K(t) ready; Vbuf consumed by prev tile
    stageV(t * 64);    // V(t) in flight; drains at the mid barrier

    const char* Kt = (const char*)&Kbuf[buf][0];

    // S = q.k^T - 4 (C-init). Fixed-max softmax: scores exp2-domain
    // ~N(0,0.59), global max ~3.7 < 4 -> p in (0,1]; offset-invariant.
    f32x4 s[4];
    #pragma unroll
    for (int jt = 0; jt < 4; ++jt) s[jt] = f32x4{-4.f, -4.f, -4.f, -4.f};
    __builtin_amdgcn_s_setprio(1);
    #pragma unroll
    for (int c = 0; c < 2; ++c) {
      #pragma unroll
      for (int jt = 0; jt < 4; ++jt) {
        const bf16x8 bk = *(const bf16x8*)(Kt +
            swz128((jt * 16 + l16) * 128 + c * 64 + lhi * 16));
        s[jt] = __builtin_amdgcn_mfma_f32_16x16x32_bf16(aq[c], bk, s[jt], 0, 0, 0);
      }
    }
    __builtin_amdgcn_s_setprio(0);

    #pragma unroll
    for (int jt = 0; jt < 4; ++jt)
      #pragma unroll
      for (int r = 0; r < 4; ++r)
        s[jt][r] = __builtin_amdgcn_exp2f(s[jt][r]);

    // P -> per-wave LDS (C-layout -> A-layout transpose), swizzled.
    char* Pw = (char*)&Pl[w][0];
    #pragma unroll
    for (int jt = 0; jt < 4; ++jt)
      #pragma unroll
      for (int r = 0; r < 4; ++r) {
        union { float f; unsigned u; } pv;
        pv.f = s[jt][r];
        *(u16*)(Pw + swz128((lhi * 4 + r) * 128 + (jt * 16 + l16) * 2)) =
            (u16)((pv.u + 0x8000u) >> 16);
      }

    __syncthreads();   // V(t) ready
    if (t < 31) stageK(buf ^ 1, (t + 1) * 64);

    const char* Vt = (const char*)&Vbuf[0];

    // O += P @ V ; row-sum via ones-B MFMA
    __builtin_amdgcn_s_setprio(1);
    #pragma unroll
    for (int c = 0; c < 2; ++c) {
      const bf16x8 ap = *(const bf16x8*)(Pw +
          swz128(l16 * 128 + c * 64 + lhi * 16));
      acc_l = __builtin_amdgcn_mfma_f32_16x16x32_bf16(ap, ones, acc_l, 0, 0, 0);
      #pragma unroll
      for (int dt = 0; dt < 4; ++dt) {
        const bf16x8 bv = *(const bf16x8*)(Vt +
            swz128((dt * 16 + l16) * 128 + c * 64 + lhi * 16));
        acc_o[dt] = __builtin_amdgcn_mfma_f32_16x16x32_bf16(ap, bv, acc_o[dt], 0, 0, 0);
      }
    }
    __builtin_amdgcn_s_setprio(0);
  }

  // faithful-reshape write: row = h*128 + t/16, col = (t%16)*64 + d
  #pragma unroll
  for (int dt = 0; dt < 4; ++dt) {
    #pragma unroll
    for (int r = 0; r < 4; ++r) {
      const int t = qr0 + lhi * 4 + r;
      const int d = dt * 16 + l16;
      const float v = acc_o[dt][r] / acc_l[r];
      const int rr = h * 128 + (t >> 4);
      const int cc = ((t & 15) << 6) + d;
      outPre[((size_t)b * 2048 + rr) * 1024 + cc] = f2bf(v);
    }
  }
}

extern "C" void kernel_launch(void* const* d_in, const int* in_sizes, int n_in,
                              void* d_out, int out_size, void* d_ws, size_t ws_size,
                              hipStream_t stream) {
  const float* Q  = (const float*)d_in[0];
  const float* K  = (const float*)d_in[1];
  const float* V  = (const float*)d_in[2];
  const float* Wq = (const float*)d_in[3];
  const float* bq = (const float*)d_in[4];
  const float* Wk = (const float*)d_in[5];
  const float* bk = (const float*)d_in[6];
  const float* Wv = (const float*)d_in[7];
  const float* bv = (const float*)d_in[8];
  const float* Wo = (const float*)d_in[9];
  const float* bo = (const float*)d_in[10];

  char* ws = (char*)d_ws;
  const size_t ACT = 16777216;              // 8192*1024 bf16 = 16MB
  const size_t WSZ = 2097152;               // 1024*1024 bf16 = 2MB
  u16* act = (u16*)(ws);                    // outPre (attn output, phase 3+)
  u16* qhd = (u16*)(ws + ACT);
  u16* khd = (u16*)(ws + 2 * ACT);
  u16* vtd = (u16*)(ws + 3 * ACT);
  u16* wtq = (u16*)(ws + 4 * ACT);
  u16* wtk = (u16*)(ws + 4 * ACT + WSZ);
  u16* wtv = (u16*)(ws + 4 * ACT + 2 * WSZ);
  u16* wto = (u16*)(ws + 4 * ACT + 3 * WSZ);

  const int cvtBlocks = 8388608 / 16 / 256;  // 2048 blocks per input

  // 1) all 4 weight transposes, one dispatch
  transpose_cvt4_kernel<<<dim3(32, 32, 4), dim3(32, 8), 0, stream>>>(
      Wq, Wk, Wv, Wo, wtq, wtk, wtv, wto);

  const size_t needBig = 4 * ACT + 4 * WSZ + 2 * ACT;  // 104 MB
  if (ws_size >= needBig) {
    // 2) batched path: one cvt3 dispatch into three coexisting A buffers,
    //    then three back-to-back GEMMs (saves 2 launch gaps + 2 ramp-downs).
    u16* abfQ = act;                                   // overlays outPre
    u16* abfK = (u16*)(ws + 4 * ACT + 4 * WSZ);
    u16* abfV = (u16*)(ws + 4 * ACT + 4 * WSZ + ACT);
    cvt3_bf16_kernel<<<dim3(cvtBlocks, 1, 3), 256, 0, stream>>>(
        Q, K, V, abfQ, abfK, abfV);
    gemm128_kernel<0><<<512, 512, 0, stream>>>(abfQ, wtq, bq, qhd);
    gemm128_kernel<1><<<512, 512, 0, stream>>>(abfK, wtk, bk, khd);
    gemm128_kernel<2><<<512, 512, 0, stream>>>(abfV, wtv, bv, vtd);
  } else {
    // serial fallback (r17-proven): one abf buffer reused
    u16* abf = act;
    cvt_bf16_kernel<<<cvtBlocks, 256, 0, stream>>>(Q, abf);
    gemm128_kernel<0><<<512, 512, 0, stream>>>(abf, wtq, bq, qhd);
    cvt_bf16_kernel<<<cvtBlocks, 256, 0, stream>>>(K, abf);
    gemm128_kernel<1><<<512, 512, 0, stream>>>(abf, wtk, bk, khd);
    cvt_bf16_kernel<<<cvtBlocks, 256, 0, stream>>>(V, abf);
    gemm128_kernel<2><<<512, 512, 0, stream>>>(abf, wtv, bv, vtd);
  }

  // 3) attention -> outPre (clobbers abfQ region, already consumed)
  attn_kernel<<<1024, 512, 0, stream>>>(qhd, khd, vtd, act);
  // 4) out = outPre @ Wo + bo (f32)
  gemm128_kernel<3><<<512, 512, 0, stream>>>(act, wto, bo, (float*)d_out);
}